// Round 12
// baseline (197.234 us; speedup 1.0000x reference)
//
#include <hip/hip_runtime.h>

typedef float  f32x4  __attribute__((ext_vector_type(4)));
typedef short  short8 __attribute__((ext_vector_type(8)));
typedef unsigned short ushort_t;
typedef ushort_t us4   __attribute__((ext_vector_type(4)));

#define NCOARSE 1024
#define NFINE   4096

__device__ __forceinline__ ushort_t f2bf(float f){
  union { float f; unsigned u; } a; a.f = f;
  unsigned u = a.u;
  return (ushort_t)((u + 0x7fffu + ((u >> 16) & 1u)) >> 16);
}

__device__ __forceinline__ f32x4 splat4(float v){ f32x4 t = {v, v, v, v}; return t; }

// ---- pack fp32 row-major W[K][256] into bf16, MFMA-B-fragment order.
__global__ void prep_w(const float* __restrict__ W, ushort_t* __restrict__ Wp, int nelem){
  int e = blockIdx.x * 256 + threadIdx.x;
  if (e >= nelem) return;
  int j    = e & 7;
  int lane = (e >> 3) & 63;
  int g    = e >> 9;
  int nb   = g & 15;
  int kc   = g >> 4;
  int k = kc * 32 + (lane >> 4) * 8 + j;
  int n = nb * 16 + (lane & 15);
  Wp[e] = f2bf(W[k * 256 + n]);
}

// ---- kNN, reference fp32 arithmetic EXACTLY (expansion form, no fma).
__global__ __launch_bounds__(256) void knn_kernel(const float* __restrict__ pos,
                           const float* __restrict__ pos_skip,
                           int* __restrict__ knn_i, float* __restrict__ knn_w){
  __shared__ f32x4 cand[8][129];
  const int tid = threadIdx.x;
  const int b   = blockIdx.x >> 6;
  const int mA  = blockIdx.x * 64 + (tid >> 3);
  const int mB  = mA + 32;
  const int chunk = tid & 7;

  const float* p = pos + (size_t)b * NCOARSE * 3;
  for (int c = tid; c < NCOARSE; c += 256){
    float x = p[3*c], y = p[3*c+1], z = p[3*c+2];
    float sc = __fadd_rn(__fadd_rn(__fmul_rn(x,x), __fmul_rn(y,y)), __fmul_rn(z,z));
    f32x4 v = { x, y, z, sc };
    cand[c >> 7][c & 127] = v;
  }
  __syncthreads();

  const float* qA = pos_skip + (size_t)mA * 3;
  const float* qB = pos_skip + (size_t)mB * 3;
  float ax = qA[0], ay = qA[1], az = qA[2];
  float bx = qB[0], by = qB[1], bz = qB[2];
  float sfA = __fadd_rn(__fadd_rn(__fmul_rn(ax,ax), __fmul_rn(ay,ay)), __fmul_rn(az,az));
  float sfB = __fadd_rn(__fadd_rn(__fmul_rn(bx,bx), __fmul_rn(by,by)), __fmul_rn(bz,bz));

  float dA0 = 1e30f, dA1 = 1e30f, dA2 = 1e30f;
  int   iA0 = 0,     iA1 = 0,     iA2 = 0;
  float dB0 = 1e30f, dB1 = 1e30f, dB2 = 1e30f;
  int   iB0 = 0,     iB1 = 0,     iB2 = 0;
  const int gbase = chunk * 128;
  #pragma unroll 2
  for (int i = 0; i < 128; ++i){
    f32x4 v = cand[chunk][i];
    int gi = gbase + i;
    float dotA = __fadd_rn(__fadd_rn(__fmul_rn(ax, v.x), __fmul_rn(ay, v.y)),
                           __fmul_rn(az, v.z));
    float dA = fmaxf(__fsub_rn(__fadd_rn(sfA, v.w), __fmul_rn(2.0f, dotA)), 0.0f);
    if (dA < dA2){
      if (dA < dA1){
        dA2 = dA1; iA2 = iA1;
        if (dA < dA0){ dA1 = dA0; iA1 = iA0; dA0 = dA; iA0 = gi; }
        else         { dA1 = dA;  iA1 = gi; }
      } else { dA2 = dA; iA2 = gi; }
    }
    float dotB = __fadd_rn(__fadd_rn(__fmul_rn(bx, v.x), __fmul_rn(by, v.y)),
                           __fmul_rn(bz, v.z));
    float dB = fmaxf(__fsub_rn(__fadd_rn(sfB, v.w), __fmul_rn(2.0f, dotB)), 0.0f);
    if (dB < dB2){
      if (dB < dB1){
        dB2 = dB1; iB2 = iB1;
        if (dB < dB0){ dB1 = dB0; iB1 = iB0; dB0 = dB; iB0 = gi; }
        else         { dB1 = dB;  iB1 = gi; }
      } else { dB2 = dB; iB2 = gi; }
    }
  }

  #pragma unroll
  for (int mlev = 1; mlev <= 4; mlev <<= 1){
    float e0 = __shfl_xor(dA0, mlev), e1 = __shfl_xor(dA1, mlev), e2 = __shfl_xor(dA2, mlev);
    int   j0 = __shfl_xor(iA0, mlev), j1 = __shfl_xor(iA1, mlev), j2 = __shfl_xor(iA2, mlev);
    #pragma unroll
    for (int s = 0; s < 3; ++s){
      float e = (s == 0) ? e0 : (s == 1) ? e1 : e2;
      int   j = (s == 0) ? j0 : (s == 1) ? j1 : j2;
      bool l2 = (e < dA2) || (e == dA2 && j < iA2);
      if (l2){
        bool l1 = (e < dA1) || (e == dA1 && j < iA1);
        if (l1){
          dA2 = dA1; iA2 = iA1;
          bool l0 = (e < dA0) || (e == dA0 && j < iA0);
          if (l0){ dA1 = dA0; iA1 = iA0; dA0 = e; iA0 = j; }
          else   { dA1 = e;  iA1 = j; }
        } else { dA2 = e; iA2 = j; }
      }
    }
    float f0 = __shfl_xor(dB0, mlev), f1 = __shfl_xor(dB1, mlev), f2 = __shfl_xor(dB2, mlev);
    int   k0 = __shfl_xor(iB0, mlev), k1 = __shfl_xor(iB1, mlev), k2 = __shfl_xor(iB2, mlev);
    #pragma unroll
    for (int s = 0; s < 3; ++s){
      float e = (s == 0) ? f0 : (s == 1) ? f1 : f2;
      int   j = (s == 0) ? k0 : (s == 1) ? k1 : k2;
      bool l2 = (e < dB2) || (e == dB2 && j < iB2);
      if (l2){
        bool l1 = (e < dB1) || (e == dB1 && j < iB1);
        if (l1){
          dB2 = dB1; iB2 = iB1;
          bool l0 = (e < dB0) || (e == dB0 && j < iB0);
          if (l0){ dB1 = dB0; iB1 = iB0; dB0 = e; iB0 = j; }
          else   { dB1 = e;  iB1 = j; }
        } else { dB2 = e; iB2 = j; }
      }
    }
  }

  if (chunk == 0){
    {
      float w0 = 1.0f / fmaxf(dA0, 1e-16f);
      float w1 = 1.0f / fmaxf(dA1, 1e-16f);
      float w2 = 1.0f / fmaxf(dA2, 1e-16f);
      float ws = __fadd_rn(__fadd_rn(w0, w1), w2);
      knn_i[3*mA]   = b * NCOARSE + iA0;
      knn_i[3*mA+1] = b * NCOARSE + iA1;
      knn_i[3*mA+2] = b * NCOARSE + iA2;
      knn_w[3*mA]   = w0 / ws;
      knn_w[3*mA+1] = w1 / ws;
      knn_w[3*mA+2] = w2 / ws;
    }
    {
      float w0 = 1.0f / fmaxf(dB0, 1e-16f);
      float w1 = 1.0f / fmaxf(dB1, 1e-16f);
      float w2 = 1.0f / fmaxf(dB2, 1e-16f);
      float ws = __fadd_rn(__fadd_rn(w0, w1), w2);
      knn_i[3*mB]   = b * NCOARSE + iB0;
      knn_i[3*mB+1] = b * NCOARSE + iB1;
      knn_i[3*mB+2] = b * NCOARSE + iB2;
      knn_w[3*mB]   = w0 / ws;
      knn_w[3*mB+1] = w1 / ws;
      knn_w[3*mB+2] = w2 / ws;
    }
  }
}

#define LDW4(DST, WP, STEP)                                                   \
  { _Pragma("unroll")                                                         \
    for (int n_ = 0; n_ < 4; ++n_)                                            \
      DST[n_] = *(const short8*)((WP) +                                       \
          ((size_t)(((STEP) * 16 + wp * 4 + n_) * 64 + lane)) * 8); }

// ---- REAL fused kernel (r10 verbatim, known 56us / passing) ----
__global__ __launch_bounds__(256, 3)
void fused_fp(const float* __restrict__ x, const float* __restrict__ x_skip,
              const int* __restrict__ knn_i, const float* __restrict__ knn_w,
              const ushort_t* __restrict__ W1p, const float* __restrict__ b1,
              const ushort_t* __restrict__ W2p, const float* __restrict__ b2,
              float* __restrict__ out){
  __shared__ ushort_t hbuf[32 * 384];
  char* h1b = (char*)hbuf;
  char* h2b = (char*)hbuf;
  const int tid  = threadIdx.x;
  const int lb   = ((blockIdx.x & 7) << 8) + (blockIdx.x >> 3);
  const int row0 = lb * 32;
  const int wp   = tid >> 6;
  const int lane = tid & 63;
  const int lhi  = lane >> 4;
  const int llo  = lane & 15;

  {
    const int r   = tid >> 3;
    const int sub = tid & 7;
    const int m   = row0 + r;
    const f32x4* xsr = (const f32x4*)(x_skip + (size_t)m * 128);
    f32x4 xs[4];
    #pragma unroll
    for (int it = 0; it < 4; ++it) xs[it] = xsr[it * 8 + sub];
    int i0 = knn_i[3*m], i1 = knn_i[3*m+1], i2 = knn_i[3*m+2];
    float w0 = knn_w[3*m], w1 = knn_w[3*m+1], w2 = knn_w[3*m+2];
    const f32x4* x0 = (const f32x4*)(x + (size_t)i0 * 256);
    const f32x4* x1 = (const f32x4*)(x + (size_t)i1 * 256);
    const f32x4* x2 = (const f32x4*)(x + (size_t)i2 * 256);
    #pragma unroll
    for (int it = 0; it < 8; ++it){
      int c4 = it * 8 + sub;
      f32x4 v = x0[c4] * w0 + x1[c4] * w1 + x2[c4] * w2;
      int byte = (r * 768 + c4 * 8) ^ ((r & 7) << 4);
      us4 pk = { f2bf(v.x), f2bf(v.y), f2bf(v.z), f2bf(v.w) };
      *(us4*)(h1b + byte) = pk;
    }
    #pragma unroll
    for (int it = 0; it < 4; ++it){
      int c4 = it * 8 + sub;
      f32x4 v = xs[it];
      int byte = (r * 768 + 512 + c4 * 8) ^ ((r & 7) << 4);
      us4 pk = { f2bf(v.x), f2bf(v.y), f2bf(v.z), f2bf(v.w) };
      *(us4*)(h1b + byte) = pk;
    }
  }
  __syncthreads();

  f32x4 acc[2][4];
  #pragma unroll
  for (int nbp = 0; nbp < 4; ++nbp){
    float bb = b1[wp * 64 + nbp * 16 + llo];
    #pragma unroll
    for (int mb = 0; mb < 2; ++mb) acc[mb][nbp] = splat4(bb);
  }
  {
    short8 wr[3][4];
    LDW4(wr[0], W1p, 0);
    LDW4(wr[1], W1p, 1);
    LDW4(wr[2], W1p, 2);
    #pragma unroll
    for (int kk = 0; kk < 12; ++kk){
      short8 af[2];
      #pragma unroll
      for (int mb = 0; mb < 2; ++mb){
        int rr = mb * 16 + llo;
        int byte = (rr * 768 + kk * 64 + lhi * 16) ^ ((rr & 7) << 4);
        af[mb] = *(const short8*)(h1b + byte);
      }
      #pragma unroll
      for (int mb = 0; mb < 2; ++mb)
        #pragma unroll
        for (int nbp = 0; nbp < 4; ++nbp)
          acc[mb][nbp] = __builtin_amdgcn_mfma_f32_16x16x32_bf16(
              af[mb], wr[kk % 3][nbp], acc[mb][nbp], 0, 0, 0);
      if (kk + 3 < 12) { LDW4(wr[kk % 3], W1p, kk + 3); }
    }
  }
  __syncthreads();

  #pragma unroll
  for (int mb = 0; mb < 2; ++mb)
    #pragma unroll
    for (int nbp = 0; nbp < 4; ++nbp)
      #pragma unroll
      for (int rg = 0; rg < 4; ++rg){
        int rr  = mb * 16 + lhi * 4 + rg;
        int col = wp * 64 + nbp * 16 + llo;
        int byte = (rr * 512 + col * 2) ^ ((rr & 7) << 4);
        *(ushort_t*)(h2b + byte) = f2bf(fmaxf(acc[mb][nbp][rg], 0.0f));
      }
  __syncthreads();

  f32x4 acc2[2][4];
  #pragma unroll
  for (int nbp = 0; nbp < 4; ++nbp){
    float bb = b2[wp * 64 + nbp * 16 + llo];
    #pragma unroll
    for (int mb = 0; mb < 2; ++mb) acc2[mb][nbp] = splat4(bb);
  }
  {
    short8 wr[3][4];
    LDW4(wr[0], W2p, 0);
    LDW4(wr[1], W2p, 1);
    LDW4(wr[2], W2p, 2);
    #pragma unroll
    for (int kk = 0; kk < 8; ++kk){
      short8 af[2];
      #pragma unroll
      for (int mb = 0; mb < 2; ++mb){
        int rr = mb * 16 + llo;
        int byte = (rr * 512 + kk * 64 + lhi * 16) ^ ((rr & 7) << 4);
        af[mb] = *(const short8*)(h2b + byte);
      }
      #pragma unroll
      for (int mb = 0; mb < 2; ++mb)
        #pragma unroll
        for (int nbp = 0; nbp < 4; ++nbp)
          acc2[mb][nbp] = __builtin_amdgcn_mfma_f32_16x16x32_bf16(
              af[mb], wr[kk % 3][nbp], acc2[mb][nbp], 0, 0, 0);
      if (kk + 3 < 8) { LDW4(wr[kk % 3], W2p, kk + 3); }
    }
  }

  #pragma unroll
  for (int mb = 0; mb < 2; ++mb)
    #pragma unroll
    for (int nbp = 0; nbp < 4; ++nbp)
      #pragma unroll
      for (int rg = 0; rg < 4; ++rg){
        int row = row0 + mb * 16 + lhi * 4 + rg;
        int col = wp * 64 + nbp * 16 + llo;
        out[(size_t)row * 256 + col] = fmaxf(acc2[mb][nbp][rg], 0.0f);
      }
}

// ============ ABLATION VARIANTS (write only to ws; diagnosis) ============

// V2: no W loads — constant B fragment. Isolates W-load stall.
__global__ __launch_bounds__(256, 3)
void abl_noW(const float* __restrict__ x, const float* __restrict__ x_skip,
             const int* __restrict__ knn_i, const float* __restrict__ knn_w,
             const float* __restrict__ b1, const float* __restrict__ b2,
             float* __restrict__ wsout){
  __shared__ ushort_t hbuf[32 * 384];
  char* h1b = (char*)hbuf;
  char* h2b = (char*)hbuf;
  const int tid  = threadIdx.x;
  const int lb   = ((blockIdx.x & 7) << 8) + (blockIdx.x >> 3);
  const int row0 = lb * 32;
  const int wp   = tid >> 6;
  const int lane = tid & 63;
  const int lhi  = lane >> 4;
  const int llo  = lane & 15;

  {
    const int r   = tid >> 3;
    const int sub = tid & 7;
    const int m   = row0 + r;
    const f32x4* xsr = (const f32x4*)(x_skip + (size_t)m * 128);
    f32x4 xs[4];
    #pragma unroll
    for (int it = 0; it < 4; ++it) xs[it] = xsr[it * 8 + sub];
    int i0 = knn_i[3*m], i1 = knn_i[3*m+1], i2 = knn_i[3*m+2];
    float w0 = knn_w[3*m], w1 = knn_w[3*m+1], w2 = knn_w[3*m+2];
    const f32x4* x0 = (const f32x4*)(x + (size_t)i0 * 256);
    const f32x4* x1 = (const f32x4*)(x + (size_t)i1 * 256);
    const f32x4* x2 = (const f32x4*)(x + (size_t)i2 * 256);
    #pragma unroll
    for (int it = 0; it < 8; ++it){
      int c4 = it * 8 + sub;
      f32x4 v = x0[c4] * w0 + x1[c4] * w1 + x2[c4] * w2;
      int byte = (r * 768 + c4 * 8) ^ ((r & 7) << 4);
      us4 pk = { f2bf(v.x), f2bf(v.y), f2bf(v.z), f2bf(v.w) };
      *(us4*)(h1b + byte) = pk;
    }
    #pragma unroll
    for (int it = 0; it < 4; ++it){
      int c4 = it * 8 + sub;
      f32x4 v = xs[it];
      int byte = (r * 768 + 512 + c4 * 8) ^ ((r & 7) << 4);
      us4 pk = { f2bf(v.x), f2bf(v.y), f2bf(v.z), f2bf(v.w) };
      *(us4*)(h1b + byte) = pk;
    }
  }
  __syncthreads();

  const short8 cw = { (short)0x3F80, (short)0x3F80, (short)0x3F80, (short)0x3F80,
                      (short)0x3F80, (short)0x3F80, (short)0x3F80, (short)0x3F80 };

  f32x4 acc[2][4];
  #pragma unroll
  for (int nbp = 0; nbp < 4; ++nbp){
    float bb = b1[wp * 64 + nbp * 16 + llo];
    #pragma unroll
    for (int mb = 0; mb < 2; ++mb) acc[mb][nbp] = splat4(bb);
  }
  #pragma unroll
  for (int kk = 0; kk < 12; ++kk){
    short8 af[2];
    #pragma unroll
    for (int mb = 0; mb < 2; ++mb){
      int rr = mb * 16 + llo;
      int byte = (rr * 768 + kk * 64 + lhi * 16) ^ ((rr & 7) << 4);
      af[mb] = *(const short8*)(h1b + byte);
    }
    #pragma unroll
    for (int mb = 0; mb < 2; ++mb)
      #pragma unroll
      for (int nbp = 0; nbp < 4; ++nbp)
        acc[mb][nbp] = __builtin_amdgcn_mfma_f32_16x16x32_bf16(
            af[mb], cw, acc[mb][nbp], 0, 0, 0);
  }
  __syncthreads();

  #pragma unroll
  for (int mb = 0; mb < 2; ++mb)
    #pragma unroll
    for (int nbp = 0; nbp < 4; ++nbp)
      #pragma unroll
      for (int rg = 0; rg < 4; ++rg){
        int rr  = mb * 16 + lhi * 4 + rg;
        int col = wp * 64 + nbp * 16 + llo;
        int byte = (rr * 512 + col * 2) ^ ((rr & 7) << 4);
        *(ushort_t*)(h2b + byte) = f2bf(fmaxf(acc[mb][nbp][rg], 0.0f));
      }
  __syncthreads();

  f32x4 acc2[2][4];
  #pragma unroll
  for (int nbp = 0; nbp < 4; ++nbp){
    float bb = b2[wp * 64 + nbp * 16 + llo];
    #pragma unroll
    for (int mb = 0; mb < 2; ++mb) acc2[mb][nbp] = splat4(bb);
  }
  #pragma unroll
  for (int kk = 0; kk < 8; ++kk){
    short8 af[2];
    #pragma unroll
    for (int mb = 0; mb < 2; ++mb){
      int rr = mb * 16 + llo;
      int byte = (rr * 512 + kk * 64 + lhi * 16) ^ ((rr & 7) << 4);
      af[mb] = *(const short8*)(h2b + byte);
    }
    #pragma unroll
    for (int mb = 0; mb < 2; ++mb)
      #pragma unroll
      for (int nbp = 0; nbp < 4; ++nbp)
        acc2[mb][nbp] = __builtin_amdgcn_mfma_f32_16x16x32_bf16(
            af[mb], cw, acc2[mb][nbp], 0, 0, 0);
  }

  #pragma unroll
  for (int mb = 0; mb < 2; ++mb)
    #pragma unroll
    for (int nbp = 0; nbp < 4; ++nbp)
      #pragma unroll
      for (int rg = 0; rg < 4; ++rg){
        int row = (row0 + mb * 16 + lhi * 4 + rg) & 16383;
        int col = wp * 64 + nbp * 16 + llo;
        wsout[(size_t)row * 256 + col] = fmaxf(acc2[mb][nbp][rg], 0.0f);
      }
}

// V3: no gather loads — h1 filled with constants; W loads intact.
__global__ __launch_bounds__(256, 3)
void abl_noGather(const ushort_t* __restrict__ W1p, const float* __restrict__ b1,
                  const ushort_t* __restrict__ W2p, const float* __restrict__ b2,
                  float* __restrict__ wsout){
  __shared__ ushort_t hbuf[32 * 384];
  char* h1b = (char*)hbuf;
  char* h2b = (char*)hbuf;
  const int tid  = threadIdx.x;
  const int lb   = ((blockIdx.x & 7) << 8) + (blockIdx.x >> 3);
  const int row0 = lb * 32;
  const int wp   = tid >> 6;
  const int lane = tid & 63;
  const int lhi  = lane >> 4;
  const int llo  = lane & 15;

  {
    const int r   = tid >> 3;
    const int sub = tid & 7;
    const us4 pk = { 0x3C00, 0x3C00, 0x3C00, 0x3C00 };
    #pragma unroll
    for (int it = 0; it < 8; ++it){
      int c4 = it * 8 + sub;
      int byte = (r * 768 + c4 * 8) ^ ((r & 7) << 4);
      *(us4*)(h1b + byte) = pk;
    }
    #pragma unroll
    for (int it = 0; it < 4; ++it){
      int c4 = it * 8 + sub;
      int byte = (r * 768 + 512 + c4 * 8) ^ ((r & 7) << 4);
      *(us4*)(h1b + byte) = pk;
    }
  }
  __syncthreads();

  f32x4 acc[2][4];
  #pragma unroll
  for (int nbp = 0; nbp < 4; ++nbp){
    float bb = b1[wp * 64 + nbp * 16 + llo];
    #pragma unroll
    for (int mb = 0; mb < 2; ++mb) acc[mb][nbp] = splat4(bb);
  }
  {
    short8 wr[3][4];
    LDW4(wr[0], W1p, 0);
    LDW4(wr[1], W1p, 1);
    LDW4(wr[2], W1p, 2);
    #pragma unroll
    for (int kk = 0; kk < 12; ++kk){
      short8 af[2];
      #pragma unroll
      for (int mb = 0; mb < 2; ++mb){
        int rr = mb * 16 + llo;
        int byte = (rr * 768 + kk * 64 + lhi * 16) ^ ((rr & 7) << 4);
        af[mb] = *(const short8*)(h1b + byte);
      }
      #pragma unroll
      for (int mb = 0; mb < 2; ++mb)
        #pragma unroll
        for (int nbp = 0; nbp < 4; ++nbp)
          acc[mb][nbp] = __builtin_amdgcn_mfma_f32_16x16x32_bf16(
              af[mb], wr[kk % 3][nbp], acc[mb][nbp], 0, 0, 0);
      if (kk + 3 < 12) { LDW4(wr[kk % 3], W1p, kk + 3); }
    }
  }
  __syncthreads();

  #pragma unroll
  for (int mb = 0; mb < 2; ++mb)
    #pragma unroll
    for (int nbp = 0; nbp < 4; ++nbp)
      #pragma unroll
      for (int rg = 0; rg < 4; ++rg){
        int rr  = mb * 16 + lhi * 4 + rg;
        int col = wp * 64 + nbp * 16 + llo;
        int byte = (rr * 512 + col * 2) ^ ((rr & 7) << 4);
        *(ushort_t*)(h2b + byte) = f2bf(fmaxf(acc[mb][nbp][rg], 0.0f));
      }
  __syncthreads();

  f32x4 acc2[2][4];
  #pragma unroll
  for (int nbp = 0; nbp < 4; ++nbp){
    float bb = b2[wp * 64 + nbp * 16 + llo];
    #pragma unroll
    for (int mb = 0; mb < 2; ++mb) acc2[mb][nbp] = splat4(bb);
  }
  {
    short8 wr[3][4];
    LDW4(wr[0], W2p, 0);
    LDW4(wr[1], W2p, 1);
    LDW4(wr[2], W2p, 2);
    #pragma unroll
    for (int kk = 0; kk < 8; ++kk){
      short8 af[2];
      #pragma unroll
      for (int mb = 0; mb < 2; ++mb){
        int rr = mb * 16 + llo;
        int byte = (rr * 512 + kk * 64 + lhi * 16) ^ ((rr & 7) << 4);
        af[mb] = *(const short8*)(h2b + byte);
      }
      #pragma unroll
      for (int mb = 0; mb < 2; ++mb)
        #pragma unroll
        for (int nbp = 0; nbp < 4; ++nbp)
          acc2[mb][nbp] = __builtin_amdgcn_mfma_f32_16x16x32_bf16(
              af[mb], wr[kk % 3][nbp], acc2[mb][nbp], 0, 0, 0);
      if (kk + 3 < 8) { LDW4(wr[kk % 3], W2p, kk + 3); }
    }
  }

  #pragma unroll
  for (int mb = 0; mb < 2; ++mb)
    #pragma unroll
    for (int nbp = 0; nbp < 4; ++nbp)
      #pragma unroll
      for (int rg = 0; rg < 4; ++rg){
        int row = (row0 + mb * 16 + lhi * 4 + rg) & 16383;
        int col = wp * 64 + nbp * 16 + llo;
        wsout[(size_t)row * 256 + col] = fmaxf(acc2[mb][nbp][rg], 0.0f);
      }
}

// V4: all loads + stores intact, MFMAs replaced by vector-XOR keep-alives.
__global__ __launch_bounds__(256, 3)
void abl_loadsOnly(const float* __restrict__ x, const float* __restrict__ x_skip,
                   const int* __restrict__ knn_i, const float* __restrict__ knn_w,
                   const ushort_t* __restrict__ W1p,
                   const ushort_t* __restrict__ W2p,
                   float* __restrict__ wsout){
  __shared__ ushort_t hbuf[32 * 384];
  char* h1b = (char*)hbuf;
  char* h2b = (char*)hbuf;
  const int tid  = threadIdx.x;
  const int lb   = ((blockIdx.x & 7) << 8) + (blockIdx.x >> 3);
  const int row0 = lb * 32;
  const int wp   = tid >> 6;
  const int lane = tid & 63;
  const int lhi  = lane >> 4;
  const int llo  = lane & 15;

  {
    const int r   = tid >> 3;
    const int sub = tid & 7;
    const int m   = row0 + r;
    const f32x4* xsr = (const f32x4*)(x_skip + (size_t)m * 128);
    f32x4 xs[4];
    #pragma unroll
    for (int it = 0; it < 4; ++it) xs[it] = xsr[it * 8 + sub];
    int i0 = knn_i[3*m], i1 = knn_i[3*m+1], i2 = knn_i[3*m+2];
    float w0 = knn_w[3*m], w1 = knn_w[3*m+1], w2 = knn_w[3*m+2];
    const f32x4* x0 = (const f32x4*)(x + (size_t)i0 * 256);
    const f32x4* x1 = (const f32x4*)(x + (size_t)i1 * 256);
    const f32x4* x2 = (const f32x4*)(x + (size_t)i2 * 256);
    #pragma unroll
    for (int it = 0; it < 8; ++it){
      int c4 = it * 8 + sub;
      f32x4 v = x0[c4] * w0 + x1[c4] * w1 + x2[c4] * w2;
      int byte = (r * 768 + c4 * 8) ^ ((r & 7) << 4);
      us4 pk = { f2bf(v.x), f2bf(v.y), f2bf(v.z), f2bf(v.w) };
      *(us4*)(h1b + byte) = pk;
    }
    #pragma unroll
    for (int it = 0; it < 4; ++it){
      int c4 = it * 8 + sub;
      f32x4 v = xs[it];
      int byte = (r * 768 + 512 + c4 * 8) ^ ((r & 7) << 4);
      us4 pk = { f2bf(v.x), f2bf(v.y), f2bf(v.z), f2bf(v.w) };
      *(us4*)(h1b + byte) = pk;
    }
  }
  __syncthreads();

  short8 ka = { 0, 0, 0, 0, 0, 0, 0, 0 };
  #pragma unroll
  for (int kk = 0; kk < 12; ++kk){
    short8 af[2];
    #pragma unroll
    for (int mb = 0; mb < 2; ++mb){
      int rr = mb * 16 + llo;
      int byte = (rr * 768 + kk * 64 + lhi * 16) ^ ((rr & 7) << 4);
      af[mb] = *(const short8*)(h1b + byte);
    }
    short8 wv[4];
    LDW4(wv, W1p, kk);
    ka = ka ^ af[0] ^ af[1] ^ wv[0] ^ wv[1] ^ wv[2] ^ wv[3];
  }
  __syncthreads();

  #pragma unroll
  for (int mb = 0; mb < 2; ++mb)
    #pragma unroll
    for (int nbp = 0; nbp < 4; ++nbp)
      #pragma unroll
      for (int rg = 0; rg < 4; ++rg){
        int rr  = mb * 16 + lhi * 4 + rg;
        int col = wp * 64 + nbp * 16 + llo;
        int byte = (rr * 512 + col * 2) ^ ((rr & 7) << 4);
        *(ushort_t*)(h2b + byte) = (ushort_t)(ka[0] ^ (short)(rr * 37 + col));
      }
  __syncthreads();

  short8 kb = { 0, 0, 0, 0, 0, 0, 0, 0 };
  #pragma unroll
  for (int kk = 0; kk < 8; ++kk){
    short8 af[2];
    #pragma unroll
    for (int mb = 0; mb < 2; ++mb){
      int rr = mb * 16 + llo;
      int byte = (rr * 512 + kk * 64 + lhi * 16) ^ ((rr & 7) << 4);
      af[mb] = *(const short8*)(h2b + byte);
    }
    short8 wv[4];
    LDW4(wv, W2p, kk);
    kb = kb ^ af[0] ^ af[1] ^ wv[0] ^ wv[1] ^ wv[2] ^ wv[3];
  }

  float kv = (float)(short)(ka[0] ^ kb[0] ^ ka[3] ^ kb[3]);
  #pragma unroll
  for (int mb = 0; mb < 2; ++mb)
    #pragma unroll
    for (int nbp = 0; nbp < 4; ++nbp)
      #pragma unroll
      for (int rg = 0; rg < 4; ++rg){
        int row = (row0 + mb * 16 + lhi * 4 + rg) & 16383;
        int col = wp * 64 + nbp * 16 + llo;
        wsout[(size_t)row * 256 + col] = kv;
      }
}

extern "C" void kernel_launch(void* const* d_in, const int* in_sizes, int n_in,
                              void* d_out, int out_size, void* d_ws, size_t ws_size,
                              hipStream_t stream){
  (void)in_sizes; (void)n_in; (void)out_size; (void)ws_size;
  const float* x        = (const float*)d_in[0];
  const float* pos      = (const float*)d_in[1];
  const float* x_skip   = (const float*)d_in[3];
  const float* pos_skip = (const float*)d_in[4];
  const float* W1 = (const float*)d_in[6];
  const float* b1 = (const float*)d_in[7];
  const float* W2 = (const float*)d_in[8];
  const float* b2 = (const float*)d_in[9];
  float* out = (float*)d_out;
  char* ws = (char*)d_ws;
  ushort_t* W1p = (ushort_t*)(ws);                 // 196608 B
  ushort_t* W2p = (ushort_t*)(ws + 196608);        // 131072 B
  int*      ki  = (int*)(ws + 327680);             // 786432 B
  float*    kw  = (float*)(ws + 1114112);          // 786432 B
  float*    dbg = (float*)(ws + 2097152);          // 16 MB ablation sink

  hipLaunchKernelGGL(prep_w, dim3(384), dim3(256), 0, stream, W1, W1p, 98304);
  hipLaunchKernelGGL(prep_w, dim3(256), dim3(256), 0, stream, W2, W2p, 65536);
  hipLaunchKernelGGL(knn_kernel, dim3(1024), dim3(256), 0, stream, pos, pos_skip, ki, kw);
  hipLaunchKernelGGL(fused_fp, dim3(2048), dim3(256), 0, stream,
                     x, x_skip, ki, kw, W1p, b1, W2p, b2, out);
  // --- diagnosis dispatches (ws-only writes; timing via rocprof per-dispatch)
  hipLaunchKernelGGL(abl_noW, dim3(2048), dim3(256), 0, stream,
                     x, x_skip, ki, kw, b1, b2, dbg);
  hipLaunchKernelGGL(abl_noGather, dim3(2048), dim3(256), 0, stream,
                     W1p, b1, W2p, b2, dbg);
  hipLaunchKernelGGL(abl_loadsOnly, dim3(2048), dim3(256), 0, stream,
                     x, x_skip, ki, kw, W1p, W2p, dbg);
}

// Round 13
// 97.831 us; speedup vs baseline: 2.0161x; 2.0161x over previous
//
#include <hip/hip_runtime.h>

typedef float  f32x4  __attribute__((ext_vector_type(4)));
typedef short  short8 __attribute__((ext_vector_type(8)));
typedef unsigned short ushort_t;
typedef ushort_t us4   __attribute__((ext_vector_type(4)));

#define NCOARSE 1024
#define NFINE   4096

__device__ __forceinline__ ushort_t f2bf(float f){
  union { float f; unsigned u; } a; a.f = f;
  unsigned u = a.u;
  return (ushort_t)((u + 0x7fffu + ((u >> 16) & 1u)) >> 16);
}

__device__ __forceinline__ f32x4 splat4(float v){ f32x4 t = {v, v, v, v}; return t; }

// ---- pack BOTH weight matrices (bf16, MFMA-B-fragment order) in one launch.
// e in [0,98304) -> W1 (K=384); e in [98304,163840) -> W2 (K=256).
__global__ void prep_w2(const float* __restrict__ W1, const float* __restrict__ W2,
                        ushort_t* __restrict__ W1p, ushort_t* __restrict__ W2p){
  int e = blockIdx.x * 256 + threadIdx.x;        // grid 640*256 = 163840 exactly
  const float* W; ushort_t* Wp; int idx;
  if (e < 98304){ W = W1; Wp = W1p; idx = e; }
  else          { W = W2; Wp = W2p; idx = e - 98304; }
  int j    = idx & 7;
  int lane = (idx >> 3) & 63;
  int g    = idx >> 9;        // kc*16 + nb
  int nb   = g & 15;
  int kc   = g >> 4;
  int k = kc * 32 + (lane >> 4) * 8 + j;
  int n = nb * 16 + (lane & 15);
  Wp[idx] = f2bf(W[k * 256 + n]);
}

// ---- kNN (r7 1-query version), reference fp32 arithmetic EXACTLY.
__global__ __launch_bounds__(256) void knn_kernel(const float* __restrict__ pos,
                           const float* __restrict__ pos_skip,
                           int* __restrict__ knn_i, float* __restrict__ knn_w){
  __shared__ f32x4 cand[8][129];
  const int tid = threadIdx.x;
  const int b   = blockIdx.x >> 7;
  const int m   = blockIdx.x * 32 + (tid >> 3);
  const int chunk = tid & 7;

  const float* p = pos + (size_t)b * NCOARSE * 3;
  for (int c = tid; c < NCOARSE; c += 256){
    float x = p[3*c], y = p[3*c+1], z = p[3*c+2];
    float sc = __fadd_rn(__fadd_rn(__fmul_rn(x,x), __fmul_rn(y,y)), __fmul_rn(z,z));
    f32x4 v = { x, y, z, sc };
    cand[c >> 7][c & 127] = v;
  }
  __syncthreads();

  const float* q = pos_skip + (size_t)m * 3;
  float qx = q[0], qy = q[1], qz = q[2];
  float sf = __fadd_rn(__fadd_rn(__fmul_rn(qx,qx), __fmul_rn(qy,qy)), __fmul_rn(qz,qz));

  float d0 = 1e30f, d1 = 1e30f, d2 = 1e30f;
  int   i0 = 0,     i1 = 0,     i2 = 0;
  const int gbase = chunk * 128;
  #pragma unroll 4
  for (int i = 0; i < 128; ++i){
    f32x4 v = cand[chunk][i];
    float dot = __fadd_rn(__fadd_rn(__fmul_rn(qx, v.x), __fmul_rn(qy, v.y)),
                          __fmul_rn(qz, v.z));
    float d = __fsub_rn(__fadd_rn(sf, v.w), __fmul_rn(2.0f, dot));
    d = fmaxf(d, 0.0f);
    if (d < d2){
      int gi = gbase + i;
      if (d < d1){
        d2 = d1; i2 = i1;
        if (d < d0){ d1 = d0; i1 = i0; d0 = d; i0 = gi; }
        else       { d1 = d;  i1 = gi; }
      } else { d2 = d; i2 = gi; }
    }
  }

  #pragma unroll
  for (int mlev = 1; mlev <= 4; mlev <<= 1){
    float e0 = __shfl_xor(d0, mlev), e1 = __shfl_xor(d1, mlev), e2 = __shfl_xor(d2, mlev);
    int   j0 = __shfl_xor(i0, mlev), j1 = __shfl_xor(i1, mlev), j2 = __shfl_xor(i2, mlev);
    #pragma unroll
    for (int s = 0; s < 3; ++s){
      float e = (s == 0) ? e0 : (s == 1) ? e1 : e2;
      int   j = (s == 0) ? j0 : (s == 1) ? j1 : j2;
      bool l2 = (e < d2) || (e == d2 && j < i2);
      if (l2){
        bool l1 = (e < d1) || (e == d1 && j < i1);
        if (l1){
          d2 = d1; i2 = i1;
          bool l0 = (e < d0) || (e == d0 && j < i0);
          if (l0){ d1 = d0; i1 = i0; d0 = e; i0 = j; }
          else   { d1 = e;  i1 = j; }
        } else { d2 = e; i2 = j; }
      }
    }
  }

  if (chunk == 0){
    float w0 = 1.0f / fmaxf(d0, 1e-16f);
    float w1 = 1.0f / fmaxf(d1, 1e-16f);
    float w2 = 1.0f / fmaxf(d2, 1e-16f);
    float ws = __fadd_rn(__fadd_rn(w0, w1), w2);
    knn_i[3*m]   = b * NCOARSE + i0;
    knn_i[3*m+1] = b * NCOARSE + i1;
    knn_i[3*m+2] = b * NCOARSE + i2;
    knn_w[3*m]   = w0 / ws;
    knn_w[3*m+1] = w1 / ws;
    knn_w[3*m+2] = w2 / ws;
  }
}

// ---- GEMM1 (r8 structure, VGPR cap lifted): gather -> (32x384)@(384x256),
// W1 wave-slice (96 VGPR) register-resident; launch_bounds(512,2) -> cap 256,
// peak ~170 -> no spill (r8's failure was the (512,4)=128 cap).
__global__ __launch_bounds__(512, 2)
void gemm1_fp(const float* __restrict__ x, const float* __restrict__ x_skip,
              const int* __restrict__ knn_i, const float* __restrict__ knn_w,
              const ushort_t* __restrict__ W1p, const float* __restrict__ b1,
              ushort_t* __restrict__ h2p){
  __shared__ ushort_t h1[32 * 384];   // 24KB, swizzled rows (stride 768B)
  __shared__ ushort_t h2[32 * 256];   // 16KB, swizzled rows (stride 512B)
  char* h1b = (char*)h1;
  char* h2b = (char*)h2;
  const int tid  = threadIdx.x;
  const int lb   = ((blockIdx.x & 7) << 6) + (blockIdx.x >> 3);  // bijective: 512 = 8*64
  const int wq   = tid >> 6;
  const int lane = tid & 63;
  const int lhi  = lane >> 4;
  const int llo  = lane & 15;

  // W1 slice -> registers (once per block)
  short8 wfr[12][2];
  #pragma unroll
  for (int kk = 0; kk < 12; ++kk)
    #pragma unroll
    for (int nbp = 0; nbp < 2; ++nbp)
      wfr[kk][nbp] = *(const short8*)(W1p + ((size_t)((kk * 16 + wq * 2 + nbp) * 64 + lane)) * 8);
  const float bb0 = b1[wq * 32 + llo];
  const float bb1 = b1[wq * 32 + 16 + llo];

  const int r   = tid >> 4;   // gather: 16 threads per row
  const int sub = tid & 15;

  for (int t = 0; t < 4; ++t){
    const int g    = lb * 4 + t;
    const int row0 = g * 32;

    // ---- gather-stage h1
    {
      const int m = row0 + r;
      int i0 = knn_i[3*m], i1 = knn_i[3*m+1], i2 = knn_i[3*m+2];
      float w0 = knn_w[3*m], w1 = knn_w[3*m+1], w2 = knn_w[3*m+2];
      const f32x4* x0 = (const f32x4*)(x + (size_t)i0 * 256);
      const f32x4* x1 = (const f32x4*)(x + (size_t)i1 * 256);
      const f32x4* x2 = (const f32x4*)(x + (size_t)i2 * 256);
      #pragma unroll
      for (int it = 0; it < 4; ++it){
        int c4 = it * 16 + sub;
        f32x4 v = x0[c4] * w0 + x1[c4] * w1 + x2[c4] * w2;
        int byte = (r * 768 + c4 * 8) ^ ((r & 7) << 4);
        us4 pk = { f2bf(v.x), f2bf(v.y), f2bf(v.z), f2bf(v.w) };
        *(us4*)(h1b + byte) = pk;
      }
      const f32x4* xs = (const f32x4*)(x_skip + (size_t)m * 128);
      #pragma unroll
      for (int it = 0; it < 2; ++it){
        int c4 = it * 16 + sub;
        f32x4 v = xs[c4];
        int byte = (r * 768 + 512 + c4 * 8) ^ ((r & 7) << 4);
        us4 pk = { f2bf(v.x), f2bf(v.y), f2bf(v.z), f2bf(v.w) };
        *(us4*)(h1b + byte) = pk;
      }
    }
    __syncthreads();

    // ---- 12 K-steps, W from registers, A from LDS
    f32x4 acc[2][2];
    acc[0][0] = splat4(bb0); acc[1][0] = splat4(bb0);
    acc[0][1] = splat4(bb1); acc[1][1] = splat4(bb1);
    #pragma unroll
    for (int kk = 0; kk < 12; ++kk){
      short8 af[2];
      #pragma unroll
      for (int mb = 0; mb < 2; ++mb){
        int rr = mb * 16 + llo;
        int byte = (rr * 768 + kk * 64 + lhi * 16) ^ ((rr & 7) << 4);
        af[mb] = *(const short8*)(h1b + byte);
      }
      #pragma unroll
      for (int mb = 0; mb < 2; ++mb)
        #pragma unroll
        for (int nbp = 0; nbp < 2; ++nbp)
          acc[mb][nbp] = __builtin_amdgcn_mfma_f32_16x16x32_bf16(af[mb], wfr[kk][nbp], acc[mb][nbp], 0, 0, 0);
    }

    // ---- relu -> bf16 -> h2 LDS (swizzled)
    #pragma unroll
    for (int mb = 0; mb < 2; ++mb)
      #pragma unroll
      for (int nbp = 0; nbp < 2; ++nbp)
        #pragma unroll
        for (int rg = 0; rg < 4; ++rg){
          int rr  = mb * 16 + lhi * 4 + rg;
          int col = wq * 32 + nbp * 16 + llo;
          int byte = (rr * 512 + col * 2) ^ ((rr & 7) << 4);
          *(ushort_t*)(h2b + byte) = f2bf(fmaxf(acc[mb][nbp][rg], 0.0f));
        }
    __syncthreads();

    // ---- repack h2 tile -> global in A-fragment order (verified in r8)
    #pragma unroll
    for (int ss = 0; ss < 2; ++ss){
      int s   = tid * 2 + ss;          // 1024 slots: fa(0..15) x lane(0..63)
      int fa  = s >> 6;
      int l   = s & 63;
      int kk2 = fa >> 1;
      int mb2 = fa & 1;
      int row = mb2 * 16 + (l & 15);
      int byte = (row * 512 + kk2 * 64 + (l >> 4) * 16) ^ ((row & 7) << 4);
      short8 v = *(const short8*)(h2b + byte);
      *(short8*)(h2p + ((size_t)(g * 16 + fa) * 64 + l) * 8) = v;
    }
  }
}

// ---- GEMM2 (r8 structure): (65536x256)@(256x256), W2 register-resident,
// LDS-free, barrier-free; A-frags = linear coalesced 16B/lane packed reads.
__global__ __launch_bounds__(512, 3)
void gemm2_fp(const ushort_t* __restrict__ h2p,
              const ushort_t* __restrict__ W2p, const float* __restrict__ b2,
              float* __restrict__ out){
  const int tid  = threadIdx.x;
  const int lb   = ((blockIdx.x & 7) << 6) + (blockIdx.x >> 3);
  const int wq   = tid >> 6;
  const int lane = tid & 63;
  const int lhi  = lane >> 4;
  const int llo  = lane & 15;

  short8 wfr[8][2];
  #pragma unroll
  for (int kk = 0; kk < 8; ++kk)
    #pragma unroll
    for (int nbp = 0; nbp < 2; ++nbp)
      wfr[kk][nbp] = *(const short8*)(W2p + ((size_t)((kk * 16 + wq * 2 + nbp) * 64 + lane)) * 8);
  const float bb0 = b2[wq * 32 + llo];
  const float bb1 = b2[wq * 32 + 16 + llo];

  for (int t = 0; t < 4; ++t){
    const int g    = lb * 4 + t;
    const int row0 = g * 32;

    f32x4 acc[2][2];
    acc[0][0] = splat4(bb0); acc[1][0] = splat4(bb0);
    acc[0][1] = splat4(bb1); acc[1][1] = splat4(bb1);
    #pragma unroll
    for (int kk = 0; kk < 8; ++kk){
      short8 a0 = *(const short8*)(h2p + ((size_t)(g * 16 + kk * 2 + 0) * 64 + lane) * 8);
      short8 a1 = *(const short8*)(h2p + ((size_t)(g * 16 + kk * 2 + 1) * 64 + lane) * 8);
      #pragma unroll
      for (int nbp = 0; nbp < 2; ++nbp){
        acc[0][nbp] = __builtin_amdgcn_mfma_f32_16x16x32_bf16(a0, wfr[kk][nbp], acc[0][nbp], 0, 0, 0);
        acc[1][nbp] = __builtin_amdgcn_mfma_f32_16x16x32_bf16(a1, wfr[kk][nbp], acc[1][nbp], 0, 0, 0);
      }
    }

    #pragma unroll
    for (int mb = 0; mb < 2; ++mb)
      #pragma unroll
      for (int nbp = 0; nbp < 2; ++nbp)
        #pragma unroll
        for (int rg = 0; rg < 4; ++rg){
          int row = row0 + mb * 16 + lhi * 4 + rg;
          int col = wq * 32 + nbp * 16 + llo;
          out[(size_t)row * 256 + col] = fmaxf(acc[mb][nbp][rg], 0.0f);
        }
  }
}

extern "C" void kernel_launch(void* const* d_in, const int* in_sizes, int n_in,
                              void* d_out, int out_size, void* d_ws, size_t ws_size,
                              hipStream_t stream){
  (void)in_sizes; (void)n_in; (void)out_size; (void)ws_size;
  const float* x        = (const float*)d_in[0];
  const float* pos      = (const float*)d_in[1];
  const float* x_skip   = (const float*)d_in[3];
  const float* pos_skip = (const float*)d_in[4];
  const float* W1 = (const float*)d_in[6];
  const float* b1 = (const float*)d_in[7];
  const float* W2 = (const float*)d_in[8];
  const float* b2 = (const float*)d_in[9];
  float* out = (float*)d_out;
  char* ws = (char*)d_ws;
  ushort_t* W1p = (ushort_t*)(ws);                 // 196608 B
  ushort_t* W2p = (ushort_t*)(ws + 196608);        // 131072 B
  int*      ki  = (int*)(ws + 327680);             // 786432 B
  float*    kw  = (float*)(ws + 1114112);          // 786432 B
  ushort_t* h2p = (ushort_t*)(ws + 1900544);       // 33554432 B (ws>=52MB proven r5)

  hipLaunchKernelGGL(prep_w2, dim3(640), dim3(256), 0, stream, W1, W2, W1p, W2p);
  hipLaunchKernelGGL(knn_kernel, dim3(2048), dim3(256), 0, stream, pos, pos_skip, ki, kw);
  hipLaunchKernelGGL(gemm1_fp, dim3(512), dim3(512), 0, stream,
                     x, x_skip, ki, kw, W1p, b1, h2p);
  hipLaunchKernelGGL(gemm2_fp, dim3(512), dim3(512), 0, stream,
                     h2p, W2p, b2, out);
}

// Round 14
// 96.090 us; speedup vs baseline: 2.0526x; 1.0181x over previous
//
#include <hip/hip_runtime.h>

typedef float  f32x4  __attribute__((ext_vector_type(4)));
typedef short  short8 __attribute__((ext_vector_type(8)));
typedef unsigned short ushort_t;
typedef ushort_t us4   __attribute__((ext_vector_type(4)));

#define NCOARSE 1024
#define NFINE   4096

// async global->LDS, 16B per lane, wave-uniform LDS base (CDNA4 semantics)
#define GLL16(g, l)                                                   \
  __builtin_amdgcn_global_load_lds(                                   \
      (__attribute__((address_space(1))) void*)(g),                   \
      (__attribute__((address_space(3))) void*)(l), 16, 0, 0)

__device__ __forceinline__ ushort_t f2bf(float f){
  union { float f; unsigned u; } a; a.f = f;
  unsigned u = a.u;
  return (ushort_t)((u + 0x7fffu + ((u >> 16) & 1u)) >> 16);
}

__device__ __forceinline__ f32x4 splat4(float v){ f32x4 t = {v, v, v, v}; return t; }

// ---- pack BOTH weight matrices (bf16, MFMA-B-fragment order) in one launch.
__global__ void prep_w2(const float* __restrict__ W1, const float* __restrict__ W2,
                        ushort_t* __restrict__ W1p, ushort_t* __restrict__ W2p){
  int e = blockIdx.x * 256 + threadIdx.x;        // grid 640*256 = 163840 exactly
  const float* W; ushort_t* Wp; int idx;
  if (e < 98304){ W = W1; Wp = W1p; idx = e; }
  else          { W = W2; Wp = W2p; idx = e - 98304; }
  int j    = idx & 7;
  int lane = (idx >> 3) & 63;
  int g    = idx >> 9;        // kc*16 + nb
  int nb   = g & 15;
  int kc   = g >> 4;
  int k = kc * 32 + (lane >> 4) * 8 + j;
  int n = nb * 16 + (lane & 15);
  Wp[idx] = f2bf(W[k * 256 + n]);
}

// ---- kNN (r7 structure), reference fp32 arithmetic EXACTLY.
__global__ __launch_bounds__(256) void knn_kernel(const float* __restrict__ pos,
                           const float* __restrict__ pos_skip,
                           int* __restrict__ knn_i, float* __restrict__ knn_w){
  __shared__ f32x4 cand[8][129];
  const int tid = threadIdx.x;
  const int b   = blockIdx.x >> 7;
  const int m   = blockIdx.x * 32 + (tid >> 3);
  const int chunk = tid & 7;

  const float* p = pos + (size_t)b * NCOARSE * 3;
  for (int c = tid; c < NCOARSE; c += 256){
    float x = p[3*c], y = p[3*c+1], z = p[3*c+2];
    float sc = __fadd_rn(__fadd_rn(__fmul_rn(x,x), __fmul_rn(y,y)), __fmul_rn(z,z));
    f32x4 v = { x, y, z, sc };
    cand[c >> 7][c & 127] = v;
  }
  __syncthreads();

  const float* q = pos_skip + (size_t)m * 3;
  float qx = q[0], qy = q[1], qz = q[2];
  float sf = __fadd_rn(__fadd_rn(__fmul_rn(qx,qx), __fmul_rn(qy,qy)), __fmul_rn(qz,qz));

  float d0 = 1e30f, d1 = 1e30f, d2 = 1e30f;
  int   i0 = 0,     i1 = 0,     i2 = 0;
  const int gbase = chunk * 128;
  #pragma unroll 4
  for (int i = 0; i < 128; ++i){
    f32x4 v = cand[chunk][i];
    float dot = __fadd_rn(__fadd_rn(__fmul_rn(qx, v.x), __fmul_rn(qy, v.y)),
                          __fmul_rn(qz, v.z));
    float d = __fsub_rn(__fadd_rn(sf, v.w), __fmul_rn(2.0f, dot));
    d = fmaxf(d, 0.0f);
    if (d < d2){
      int gi = gbase + i;
      if (d < d1){
        d2 = d1; i2 = i1;
        if (d < d0){ d1 = d0; i1 = i0; d0 = d; i0 = gi; }
        else       { d1 = d;  i1 = gi; }
      } else { d2 = d; i2 = gi; }
    }
  }

  #pragma unroll
  for (int mlev = 1; mlev <= 4; mlev <<= 1){
    float e0 = __shfl_xor(d0, mlev), e1 = __shfl_xor(d1, mlev), e2 = __shfl_xor(d2, mlev);
    int   j0 = __shfl_xor(i0, mlev), j1 = __shfl_xor(i1, mlev), j2 = __shfl_xor(i2, mlev);
    #pragma unroll
    for (int s = 0; s < 3; ++s){
      float e = (s == 0) ? e0 : (s == 1) ? e1 : e2;
      int   j = (s == 0) ? j0 : (s == 1) ? j1 : j2;
      bool l2 = (e < d2) || (e == d2 && j < i2);
      if (l2){
        bool l1 = (e < d1) || (e == d1 && j < i1);
        if (l1){
          d2 = d1; i2 = i1;
          bool l0 = (e < d0) || (e == d0 && j < i0);
          if (l0){ d1 = d0; i1 = i0; d0 = e; i0 = j; }
          else   { d1 = e;  i1 = j; }
        } else { d2 = e; i2 = j; }
      }
    }
  }

  if (chunk == 0){
    float w0 = 1.0f / fmaxf(d0, 1e-16f);
    float w1 = 1.0f / fmaxf(d1, 1e-16f);
    float w2 = 1.0f / fmaxf(d2, 1e-16f);
    float ws = __fadd_rn(__fadd_rn(w0, w1), w2);
    knn_i[3*m]   = b * NCOARSE + i0;
    knn_i[3*m+1] = b * NCOARSE + i1;
    knn_i[3*m+2] = b * NCOARSE + i2;
    knn_w[3*m]   = w0 / ws;
    knn_w[3*m+1] = w1 / ws;
    knn_w[3*m+2] = w2 / ws;
  }
}

// ---- fused: gather -> GEMM1(relu) -> GEMM2(relu).
// W streams via global_load_lds into a 3x16KB rotating buffer, lookahead-2,
// counted vmcnt(4) + RAW s_barrier per K-step (loads stay in flight across
// barriers -- the T3/T4 pattern; __syncthreads' vmcnt(0) drain is avoided).
__global__ __launch_bounds__(256, 2)
void fused_fp(const float* __restrict__ x, const float* __restrict__ x_skip,
              const int* __restrict__ knn_i, const float* __restrict__ knn_w,
              const ushort_t* __restrict__ W1p, const float* __restrict__ b1,
              const ushort_t* __restrict__ W2p, const float* __restrict__ b2,
              float* __restrict__ out){
  __shared__ __align__(16) ushort_t hbuf[32 * 384];    // 24KB: h1, h2 overlays
  __shared__ __align__(16) ushort_t wbuf[3][8192];     // 3 x 16KB W step buffers
  char* h1b = (char*)hbuf;
  char* h2b = (char*)hbuf;
  const int tid  = threadIdx.x;
  const int lb   = ((blockIdx.x & 7) << 8) + (blockIdx.x >> 3);  // bijective: 2048 = 8*256
  const int row0 = lb * 32;
  const int wp   = tid >> 6;
  const int lane = tid & 63;
  const int lhi  = lane >> 4;
  const int llo  = lane & 15;

  // stage unified step s (0..19): W1 steps 0..11, W2 steps 12..19.
  // wave wp stages its own 4 fragments (1KB each) -> wbuf[s%3].
  auto stageW = [&](int s){
    const ushort_t* Wsel = (s < 12) ? W1p : W2p;
    int fbase = ((s < 12) ? s : (s - 12)) * 16 + wp * 4;
    #pragma unroll
    for (int i = 0; i < 4; ++i){
      const ushort_t* g = Wsel + (size_t)(fbase + i) * 512 + lane * 8;
      ushort_t* l = &wbuf[s % 3][(wp * 4 + i) * 512];
      GLL16(g, l);
    }
  };

  stageW(0);
  stageW(1);

  // ---- gather-stage h1 (overlaps the W stages): 8 threads per row
  {
    const int r   = tid >> 3;
    const int sub = tid & 7;
    const int m   = row0 + r;
    const f32x4* xsr = (const f32x4*)(x_skip + (size_t)m * 128);
    f32x4 xs[4];
    #pragma unroll
    for (int it = 0; it < 4; ++it) xs[it] = xsr[it * 8 + sub];
    int i0 = knn_i[3*m], i1 = knn_i[3*m+1], i2 = knn_i[3*m+2];
    float w0 = knn_w[3*m], w1 = knn_w[3*m+1], w2 = knn_w[3*m+2];
    const f32x4* x0 = (const f32x4*)(x + (size_t)i0 * 256);
    const f32x4* x1 = (const f32x4*)(x + (size_t)i1 * 256);
    const f32x4* x2 = (const f32x4*)(x + (size_t)i2 * 256);
    #pragma unroll
    for (int it = 0; it < 8; ++it){
      int c4 = it * 8 + sub;
      f32x4 v = x0[c4] * w0 + x1[c4] * w1 + x2[c4] * w2;
      int byte = (r * 768 + c4 * 8) ^ ((r & 7) << 4);
      us4 pk = { f2bf(v.x), f2bf(v.y), f2bf(v.z), f2bf(v.w) };
      *(us4*)(h1b + byte) = pk;
    }
    #pragma unroll
    for (int it = 0; it < 4; ++it){
      int c4 = it * 8 + sub;
      f32x4 v = xs[it];
      int byte = (r * 768 + 512 + c4 * 8) ^ ((r & 7) << 4);
      us4 pk = { f2bf(v.x), f2bf(v.y), f2bf(v.z), f2bf(v.w) };
      *(us4*)(h1b + byte) = pk;
    }
  }
  __syncthreads();    // full drain once: h1 + W steps 0,1 ready; vmcnt=0

  // ---- GEMM1: 12 K-steps
  f32x4 acc[2][4];
  #pragma unroll
  for (int nbp = 0; nbp < 4; ++nbp){
    float bb = b1[wp * 64 + nbp * 16 + llo];
    #pragma unroll
    for (int mb = 0; mb < 2; ++mb) acc[mb][nbp] = splat4(bb);
  }
  #pragma unroll
  for (int kk = 0; kk < 12; ++kk){
    asm volatile("s_waitcnt vmcnt(4)" ::: "memory");   // step kk landed; kk+1 in flight
    __builtin_amdgcn_s_barrier();                      // raw: no vmcnt(0) drain
    asm volatile("" ::: "memory");
    stageW(kk + 2);                                    // steps 2..13 (13 = W2 step 1)
    short8 af[2];
    #pragma unroll
    for (int mb = 0; mb < 2; ++mb){
      int rr = mb * 16 + llo;
      int byte = (rr * 768 + kk * 64 + lhi * 16) ^ ((rr & 7) << 4);
      af[mb] = *(const short8*)(h1b + byte);
    }
    short8 wf[4];
    #pragma unroll
    for (int nbp = 0; nbp < 4; ++nbp)
      wf[nbp] = *(const short8*)&wbuf[kk % 3][(wp * 4 + nbp) * 512 + lane * 8];
    #pragma unroll
    for (int mb = 0; mb < 2; ++mb)
      #pragma unroll
      for (int nbp = 0; nbp < 4; ++nbp)
        acc[mb][nbp] = __builtin_amdgcn_mfma_f32_16x16x32_bf16(
            af[mb], wf[nbp], acc[mb][nbp], 0, 0, 0);
  }
  __syncthreads();   // h1 reads done; drains vmcnt (steps 12,13 land)

  // ---- relu -> bf16 -> h2 (swizzled, overlays h1)
  #pragma unroll
  for (int mb = 0; mb < 2; ++mb)
    #pragma unroll
    for (int nbp = 0; nbp < 4; ++nbp)
      #pragma unroll
      for (int rg = 0; rg < 4; ++rg){
        int rr  = mb * 16 + lhi * 4 + rg;
        int col = wp * 64 + nbp * 16 + llo;
        int byte = (rr * 512 + col * 2) ^ ((rr & 7) << 4);
        *(ushort_t*)(h2b + byte) = f2bf(fmaxf(acc[mb][nbp][rg], 0.0f));
      }
  __syncthreads();

  // ---- GEMM2: 8 K-steps (unified steps 12..19)
  f32x4 acc2[2][4];
  #pragma unroll
  for (int nbp = 0; nbp < 4; ++nbp){
    float bb = b2[wp * 64 + nbp * 16 + llo];
    #pragma unroll
    for (int mb = 0; mb < 2; ++mb) acc2[mb][nbp] = splat4(bb);
  }
  #pragma unroll
  for (int t = 0; t < 8; ++t){
    const int s = 12 + t;
    if (t < 7) { asm volatile("s_waitcnt vmcnt(4)" ::: "memory"); }
    else       { asm volatile("s_waitcnt vmcnt(0)" ::: "memory"); }  // last step: full wait
    __builtin_amdgcn_s_barrier();
    asm volatile("" ::: "memory");
    if (t < 6) stageW(s + 2);                          // steps 14..19
    short8 af[2];
    #pragma unroll
    for (int mb = 0; mb < 2; ++mb){
      int rr = mb * 16 + llo;
      int byte = (rr * 512 + t * 64 + lhi * 16) ^ ((rr & 7) << 4);
      af[mb] = *(const short8*)(h2b + byte);
    }
    short8 wf[4];
    #pragma unroll
    for (int nbp = 0; nbp < 4; ++nbp)
      wf[nbp] = *(const short8*)&wbuf[s % 3][(wp * 4 + nbp) * 512 + lane * 8];
    #pragma unroll
    for (int mb = 0; mb < 2; ++mb)
      #pragma unroll
      for (int nbp = 0; nbp < 4; ++nbp)
        acc2[mb][nbp] = __builtin_amdgcn_mfma_f32_16x16x32_bf16(
            af[mb], wf[nbp], acc2[mb][nbp], 0, 0, 0);
  }

  // ---- relu -> fp32 out
  #pragma unroll
  for (int mb = 0; mb < 2; ++mb)
    #pragma unroll
    for (int nbp = 0; nbp < 4; ++nbp)
      #pragma unroll
      for (int rg = 0; rg < 4; ++rg){
        int row = row0 + mb * 16 + lhi * 4 + rg;
        int col = wp * 64 + nbp * 16 + llo;
        out[(size_t)row * 256 + col] = fmaxf(acc2[mb][nbp][rg], 0.0f);
      }
}

extern "C" void kernel_launch(void* const* d_in, const int* in_sizes, int n_in,
                              void* d_out, int out_size, void* d_ws, size_t ws_size,
                              hipStream_t stream){
  (void)in_sizes; (void)n_in; (void)out_size; (void)ws_size;
  const float* x        = (const float*)d_in[0];
  const float* pos      = (const float*)d_in[1];
  const float* x_skip   = (const float*)d_in[3];
  const float* pos_skip = (const float*)d_in[4];
  const float* W1 = (const float*)d_in[6];
  const float* b1 = (const float*)d_in[7];
  const float* W2 = (const float*)d_in[8];
  const float* b2 = (const float*)d_in[9];
  float* out = (float*)d_out;
  char* ws = (char*)d_ws;
  ushort_t* W1p = (ushort_t*)(ws);                 // 196608 B
  ushort_t* W2p = (ushort_t*)(ws + 196608);        // 131072 B
  int*      ki  = (int*)(ws + 327680);             // 786432 B
  float*    kw  = (float*)(ws + 1114112);          // 786432 B

  hipLaunchKernelGGL(prep_w2, dim3(640), dim3(256), 0, stream, W1, W2, W1p, W2p);
  hipLaunchKernelGGL(knn_kernel, dim3(2048), dim3(256), 0, stream, pos, pos_skip, ki, kw);
  hipLaunchKernelGGL(fused_fp, dim3(2048), dim3(256), 0, stream,
                     x, x_skip, ki, kw, W1p, b1, W2p, b2, out);
}

// Round 15
// 78.925 us; speedup vs baseline: 2.4990x; 1.2175x over previous
//
#include <hip/hip_runtime.h>

typedef float  f32x4  __attribute__((ext_vector_type(4)));
typedef short  short8 __attribute__((ext_vector_type(8)));
typedef unsigned short ushort_t;
typedef ushort_t us4   __attribute__((ext_vector_type(4)));

#define NCOARSE 1024
#define NFINE   4096

__device__ __forceinline__ ushort_t f2bf(float f){
  union { float f; unsigned u; } a; a.f = f;
  unsigned u = a.u;
  return (ushort_t)((u + 0x7fffu + ((u >> 16) & 1u)) >> 16);
}

__device__ __forceinline__ f32x4 splat4(float v){ f32x4 t = {v, v, v, v}; return t; }

// ---- pack BOTH weight matrices (bf16, MFMA-B-fragment order) in one launch.
__global__ void prep_w2(const float* __restrict__ W1, const float* __restrict__ W2,
                        ushort_t* __restrict__ W1p, ushort_t* __restrict__ W2p){
  int e = blockIdx.x * 256 + threadIdx.x;        // grid 640*256 = 163840 exactly
  const float* W; ushort_t* Wp; int idx;
  if (e < 98304){ W = W1; Wp = W1p; idx = e; }
  else          { W = W2; Wp = W2p; idx = e - 98304; }
  int j    = idx & 7;
  int lane = (idx >> 3) & 63;
  int g    = idx >> 9;        // kc*16 + nb
  int nb   = g & 15;
  int kc   = g >> 4;
  int k = kc * 32 + (lane >> 4) * 8 + j;
  int n = nb * 16 + (lane & 15);
  Wp[idx] = f2bf(W[k * 256 + n]);
}

#define LDW4(DST, WP, STEP)                                                   \
  { _Pragma("unroll")                                                         \
    for (int n_ = 0; n_ < 4; ++n_)                                            \
      DST[n_] = *(const short8*)((WP) +                                       \
          ((size_t)(((STEP) * 16 + wp * 4 + n_) * 64 + lane)) * 8); }

// ---- MERGED: kNN (this block's 32 rows) -> gather -> GEMM1(relu) -> GEMM2(relu)
// knn block tiling == GEMM row tiling, so the kNN result never leaves registers.
// Phase 1 reuses the h1 LDS buffer for the candidate table (16.5KB of 24KB).
// kNN fp32 arithmetic EXACTLY matches the reference (expansion form, no fma);
// butterfly merge leaves identical top-3 in ALL 8 lanes of each row group.
__global__ __launch_bounds__(256, 3)
void fp_fused(const float* __restrict__ pos, const float* __restrict__ pos_skip,
              const float* __restrict__ x, const float* __restrict__ x_skip,
              const ushort_t* __restrict__ W1p, const float* __restrict__ b1,
              const ushort_t* __restrict__ W2p, const float* __restrict__ b2,
              float* __restrict__ out){
  __shared__ __align__(16) ushort_t hbuf[32 * 384];   // 24KB: cand -> h1 -> h2
  char* h1b = (char*)hbuf;
  char* h2b = (char*)hbuf;
  f32x4* candp = (f32x4*)hbuf;                        // 8*129*16B = 16.5KB alias
  const int tid  = threadIdx.x;
  const int lb   = ((blockIdx.x & 7) << 8) + (blockIdx.x >> 3);  // bijective: 2048=8*256
  const int row0 = lb * 32;
  const int b    = lb >> 7;            // cloud id (128 blocks per cloud)
  const int wp   = tid >> 6;
  const int lane = tid & 63;
  const int lhi  = lane >> 4;
  const int llo  = lane & 15;
  const int r    = tid >> 3;           // row group (knn query AND gather row)
  const int sub  = tid & 7;            // chunk (knn) / column slice (gather)

  // ======== PHASE 1: kNN for rows row0..row0+31 (r7 arithmetic, verbatim) ====
  {
    const float* p = pos + (size_t)b * NCOARSE * 3;
    for (int c = tid; c < NCOARSE; c += 256){
      float xx = p[3*c], yy = p[3*c+1], zz = p[3*c+2];
      float sc = __fadd_rn(__fadd_rn(__fmul_rn(xx,xx), __fmul_rn(yy,yy)), __fmul_rn(zz,zz));
      f32x4 v = { xx, yy, zz, sc };
      candp[(c >> 7) * 129 + (c & 127)] = v;
    }
  }
  __syncthreads();

  float wn0, wn1, wn2;
  int   ig0, ig1, ig2;
  {
    const int m = row0 + r;
    const float* q = pos_skip + (size_t)m * 3;
    float qx = q[0], qy = q[1], qz = q[2];
    float sf = __fadd_rn(__fadd_rn(__fmul_rn(qx,qx), __fmul_rn(qy,qy)), __fmul_rn(qz,qz));

    float d0 = 1e30f, d1 = 1e30f, d2 = 1e30f;
    int   i0 = 0,     i1 = 0,     i2 = 0;
    const int gbase = sub * 128;
    #pragma unroll 4
    for (int i = 0; i < 128; ++i){
      f32x4 v = candp[sub * 129 + i];
      float dot = __fadd_rn(__fadd_rn(__fmul_rn(qx, v.x), __fmul_rn(qy, v.y)),
                            __fmul_rn(qz, v.z));
      float d = __fsub_rn(__fadd_rn(sf, v.w), __fmul_rn(2.0f, dot));
      d = fmaxf(d, 0.0f);
      if (d < d2){
        int gi = gbase + i;
        if (d < d1){
          d2 = d1; i2 = i1;
          if (d < d0){ d1 = d0; i1 = i0; d0 = d; i0 = gi; }
          else       { d1 = d;  i1 = gi; }
        } else { d2 = d; i2 = gi; }
      }
    }

    // butterfly merge across the 8 lanes of this row group; total order
    // (d, idx) lexicographic => all 8 lanes end with the identical top-3.
    #pragma unroll
    for (int mlev = 1; mlev <= 4; mlev <<= 1){
      float e0 = __shfl_xor(d0, mlev), e1 = __shfl_xor(d1, mlev), e2 = __shfl_xor(d2, mlev);
      int   j0 = __shfl_xor(i0, mlev), j1 = __shfl_xor(i1, mlev), j2 = __shfl_xor(i2, mlev);
      #pragma unroll
      for (int s = 0; s < 3; ++s){
        float e = (s == 0) ? e0 : (s == 1) ? e1 : e2;
        int   j = (s == 0) ? j0 : (s == 1) ? j1 : j2;
        bool l2 = (e < d2) || (e == d2 && j < i2);
        if (l2){
          bool l1 = (e < d1) || (e == d1 && j < i1);
          if (l1){
            d2 = d1; i2 = i1;
            bool l0 = (e < d0) || (e == d0 && j < i0);
            if (l0){ d1 = d0; i1 = i0; d0 = e; i0 = j; }
            else   { d1 = e;  i1 = j; }
          } else { d2 = e; i2 = j; }
        }
      }
    }

    float w0 = 1.0f / fmaxf(d0, 1e-16f);
    float w1 = 1.0f / fmaxf(d1, 1e-16f);
    float w2 = 1.0f / fmaxf(d2, 1e-16f);
    float ws = __fadd_rn(__fadd_rn(w0, w1), w2);
    wn0 = w0 / ws; wn1 = w1 / ws; wn2 = w2 / ws;
    ig0 = b * NCOARSE + i0; ig1 = b * NCOARSE + i1; ig2 = b * NCOARSE + i2;
  }
  __syncthreads();    // cand reads done; h1 may overlay

  // ======== PHASE 2: gather-stage h1 (idx/weights already in registers) ====
  {
    const int m = row0 + r;
    const f32x4* xsr = (const f32x4*)(x_skip + (size_t)m * 128);
    f32x4 xs[4];
    #pragma unroll
    for (int it = 0; it < 4; ++it) xs[it] = xsr[it * 8 + sub];
    const f32x4* x0 = (const f32x4*)(x + (size_t)ig0 * 256);
    const f32x4* x1 = (const f32x4*)(x + (size_t)ig1 * 256);
    const f32x4* x2 = (const f32x4*)(x + (size_t)ig2 * 256);
    #pragma unroll
    for (int it = 0; it < 8; ++it){
      int c4 = it * 8 + sub;
      f32x4 v = x0[c4] * wn0 + x1[c4] * wn1 + x2[c4] * wn2;
      int byte = (r * 768 + c4 * 8) ^ ((r & 7) << 4);
      us4 pk = { f2bf(v.x), f2bf(v.y), f2bf(v.z), f2bf(v.w) };
      *(us4*)(h1b + byte) = pk;
    }
    #pragma unroll
    for (int it = 0; it < 4; ++it){
      int c4 = it * 8 + sub;
      f32x4 v = xs[it];
      int byte = (r * 768 + 512 + c4 * 8) ^ ((r & 7) << 4);
      us4 pk = { f2bf(v.x), f2bf(v.y), f2bf(v.z), f2bf(v.w) };
      *(us4*)(h1b + byte) = pk;
    }
  }
  __syncthreads();

  // ======== GEMM1: (32x384)@(384x256) ====
  f32x4 acc[2][4];
  #pragma unroll
  for (int nbp = 0; nbp < 4; ++nbp){
    float bb = b1[wp * 64 + nbp * 16 + llo];
    #pragma unroll
    for (int mb = 0; mb < 2; ++mb) acc[mb][nbp] = splat4(bb);
  }
  {
    short8 wr[3][4];
    LDW4(wr[0], W1p, 0);
    LDW4(wr[1], W1p, 1);
    LDW4(wr[2], W1p, 2);
    #pragma unroll
    for (int kk = 0; kk < 12; ++kk){
      short8 af[2];
      #pragma unroll
      for (int mb = 0; mb < 2; ++mb){
        int rr = mb * 16 + llo;
        int byte = (rr * 768 + kk * 64 + lhi * 16) ^ ((rr & 7) << 4);
        af[mb] = *(const short8*)(h1b + byte);
      }
      #pragma unroll
      for (int mb = 0; mb < 2; ++mb)
        #pragma unroll
        for (int nbp = 0; nbp < 4; ++nbp)
          acc[mb][nbp] = __builtin_amdgcn_mfma_f32_16x16x32_bf16(
              af[mb], wr[kk % 3][nbp], acc[mb][nbp], 0, 0, 0);
      if (kk + 3 < 12) { LDW4(wr[kk % 3], W1p, kk + 3); }
    }
  }
  __syncthreads();   // all h1 reads done before h2 overlays the buffer

  // ---- relu -> bf16 -> h2 (swizzled, overlays h1)
  #pragma unroll
  for (int mb = 0; mb < 2; ++mb)
    #pragma unroll
    for (int nbp = 0; nbp < 4; ++nbp)
      #pragma unroll
      for (int rg = 0; rg < 4; ++rg){
        int rr  = mb * 16 + lhi * 4 + rg;
        int col = wp * 64 + nbp * 16 + llo;
        int byte = (rr * 512 + col * 2) ^ ((rr & 7) << 4);
        *(ushort_t*)(h2b + byte) = f2bf(fmaxf(acc[mb][nbp][rg], 0.0f));
      }
  __syncthreads();

  // ======== GEMM2: (32x256)@(256x256) ====
  f32x4 acc2[2][4];
  #pragma unroll
  for (int nbp = 0; nbp < 4; ++nbp){
    float bb = b2[wp * 64 + nbp * 16 + llo];
    #pragma unroll
    for (int mb = 0; mb < 2; ++mb) acc2[mb][nbp] = splat4(bb);
  }
  {
    short8 wr[3][4];
    LDW4(wr[0], W2p, 0);
    LDW4(wr[1], W2p, 1);
    LDW4(wr[2], W2p, 2);
    #pragma unroll
    for (int kk = 0; kk < 8; ++kk){
      short8 af[2];
      #pragma unroll
      for (int mb = 0; mb < 2; ++mb){
        int rr = mb * 16 + llo;
        int byte = (rr * 512 + kk * 64 + lhi * 16) ^ ((rr & 7) << 4);
        af[mb] = *(const short8*)(h2b + byte);
      }
      #pragma unroll
      for (int mb = 0; mb < 2; ++mb)
        #pragma unroll
        for (int nbp = 0; nbp < 4; ++nbp)
          acc2[mb][nbp] = __builtin_amdgcn_mfma_f32_16x16x32_bf16(
              af[mb], wr[kk % 3][nbp], acc2[mb][nbp], 0, 0, 0);
      if (kk + 3 < 8) { LDW4(wr[kk % 3], W2p, kk + 3); }
    }
  }

  // ---- relu -> fp32 out
  #pragma unroll
  for (int mb = 0; mb < 2; ++mb)
    #pragma unroll
    for (int nbp = 0; nbp < 4; ++nbp)
      #pragma unroll
      for (int rg = 0; rg < 4; ++rg){
        int row = row0 + mb * 16 + lhi * 4 + rg;
        int col = wp * 64 + nbp * 16 + llo;
        out[(size_t)row * 256 + col] = fmaxf(acc2[mb][nbp][rg], 0.0f);
      }
}

extern "C" void kernel_launch(void* const* d_in, const int* in_sizes, int n_in,
                              void* d_out, int out_size, void* d_ws, size_t ws_size,
                              hipStream_t stream){
  (void)in_sizes; (void)n_in; (void)out_size; (void)ws_size;
  const float* x        = (const float*)d_in[0];
  const float* pos      = (const float*)d_in[1];
  const float* x_skip   = (const float*)d_in[3];
  const float* pos_skip = (const float*)d_in[4];
  const float* W1 = (const float*)d_in[6];
  const float* b1 = (const float*)d_in[7];
  const float* W2 = (const float*)d_in[8];
  const float* b2 = (const float*)d_in[9];
  float* out = (float*)d_out;
  char* ws = (char*)d_ws;
  ushort_t* W1p = (ushort_t*)(ws);                 // 196608 B
  ushort_t* W2p = (ushort_t*)(ws + 196608);        // 131072 B

  hipLaunchKernelGGL(prep_w2, dim3(640), dim3(256), 0, stream, W1, W2, W1p, W2p);
  hipLaunchKernelGGL(fp_fused, dim3(2048), dim3(256), 0, stream,
                     pos, pos_skip, x, x_skip, W1p, b1, W2p, b2, out);
}